// Round 1
// baseline (843.406 us; speedup 1.0000x reference)
//
#include <hip/hip_runtime.h>
#include <hip/hip_bf16.h>

#define M_DIM 8192
#define N_DIM 4096
#define K_DIM 4096

typedef __attribute__((ext_vector_type(8))) short short8;
typedef __attribute__((ext_vector_type(4))) float floatx4;

// ---------------------------------------------------------------------------
// Kernel 1: global absmax of x -> ws[0] (as uint bits; x>=0 bits compare ok)
// ---------------------------------------------------------------------------
__global__ void absmax_kernel(const float4* __restrict__ x, unsigned* __restrict__ amax,
                              int n4) {
    float m = 0.0f;
    for (int i = blockIdx.x * blockDim.x + threadIdx.x; i < n4;
         i += gridDim.x * blockDim.x) {
        float4 v = x[i];
        m = fmaxf(m, fmaxf(fmaxf(fabsf(v.x), fabsf(v.y)),
                           fmaxf(fabsf(v.z), fabsf(v.w))));
    }
    // wave (64-lane) reduce
    #pragma unroll
    for (int off = 32; off > 0; off >>= 1)
        m = fmaxf(m, __shfl_down(m, off, 64));
    __shared__ float sm[4];
    if ((threadIdx.x & 63) == 0) sm[threadIdx.x >> 6] = m;
    __syncthreads();
    if (threadIdx.x == 0) {
        float b = fmaxf(fmaxf(sm[0], sm[1]), fmaxf(sm[2], sm[3]));
        atomicMax(amax, __float_as_uint(b));
    }
}

// ---------------------------------------------------------------------------
// Kernel 2: quantize x -> bf16 integers in [-127,127]
// round-half-even (rintf) matches jnp.round; values exact in bf16 so the
// fp32->bf16 conversion is a pure bit truncate (low 16 bits are zero).
// ---------------------------------------------------------------------------
__global__ void quant_kernel(const float* __restrict__ x, short* __restrict__ q,
                             const unsigned* __restrict__ amax_u, size_t n) {
    float amax = __uint_as_float(*amax_u);
    float scale = amax * (1.0f / 127.0f);
    if (scale == 0.0f) scale = 1.0f;
    size_t stride = (size_t)gridDim.x * blockDim.x * 8;
    for (size_t i = ((size_t)blockIdx.x * blockDim.x + threadIdx.x) * 8; i < n;
         i += stride) {
        float4 v0 = *(const float4*)(x + i);
        float4 v1 = *(const float4*)(x + i + 4);
        float f[8] = {v0.x, v0.y, v0.z, v0.w, v1.x, v1.y, v1.z, v1.w};
        short8 o;
        #pragma unroll
        for (int j = 0; j < 8; j++) {
            float r = rintf(f[j] / scale);
            r = fminf(127.0f, fmaxf(-128.0f, r));
            o[j] = (short)(__float_as_uint(r) >> 16);
        }
        *(short8*)(q + i) = o;
    }
}

// ---------------------------------------------------------------------------
// Kernel 3: ternary weight int32 -> bf16 (exact)
// ---------------------------------------------------------------------------
__global__ void wcvt_kernel(const int* __restrict__ w, short* __restrict__ q, size_t n) {
    size_t stride = (size_t)gridDim.x * blockDim.x * 8;
    for (size_t i = ((size_t)blockIdx.x * blockDim.x + threadIdx.x) * 8; i < n;
         i += stride) {
        int4 a = *(const int4*)(w + i);
        int4 b = *(const int4*)(w + i + 4);
        int f[8] = {a.x, a.y, a.z, a.w, b.x, b.y, b.z, b.w};
        short8 o;
        #pragma unroll
        for (int j = 0; j < 8; j++)
            o[j] = (short)(__float_as_uint((float)f[j]) >> 16);
        *(short8*)(q + i) = o;
    }
}

// ---------------------------------------------------------------------------
// Kernel 4: m97-style bf16 GEMM, B-transposed layout.
//   A: [M,K] bf16 (quantized x), B: [N,K] bf16 (W), C: [M,N] fp32
//   128x128 tile, BK=32, 4 waves (2x2), each wave 64x64 via 4x4 MFMA 16x16x32.
//   LDS layout: 8 segments of 16 rows; within a segment, chunk order == lane
//   order of the staging global_load_lds (base + lane*16), which also equals
//   the MFMA fragment lane order -> ds_read_b128 at (base + lane*16),
//   conflict-free, and satisfies the wave-uniform-base constraint.
// ---------------------------------------------------------------------------
__device__ __forceinline__ void gload16(const short* g, short* l) {
    __builtin_amdgcn_global_load_lds(
        (const __attribute__((address_space(1))) unsigned int*)g,
        (__attribute__((address_space(3))) unsigned int*)l,
        16, 0, 0);
}

__global__ __launch_bounds__(256) void gemm_bt_bf16(
    const short* __restrict__ A,   // [M,K] bf16 bits
    const short* __restrict__ B,   // [N,K] bf16 bits (ternary weight)
    float* __restrict__ C,         // [M,N]
    const float* __restrict__ bias,
    const float* __restrict__ wscale,
    const unsigned* __restrict__ amax_u) {
    __shared__ __align__(16) short As[8 * 512];  // 8 KB: 8 segs x (16 rows x 32 k)
    __shared__ __align__(16) short Bs[8 * 512];

    const int t = threadIdx.x;
    const int w = t >> 6;          // wave 0..3
    const int l = t & 63;          // lane
    const int lm = l & 15;         // fragment row/col within 16
    const int lq = l >> 4;         // quad 0..3
    const int wm = w >> 1;         // wave row 0..1
    const int wn = w & 1;          // wave col 0..1

    const int mBase = blockIdx.y * 128;
    const int nBase = blockIdx.x * 128;

    // staging: wave w owns segments {2w, 2w+1} of both A and B tiles.
    const long aRow0 = (long)(mBase + (2 * w) * 16 + lm);
    const long bRow0 = (long)(nBase + (2 * w) * 16 + lm);
    const short* aG0 = A + aRow0 * K_DIM + lq * 8;
    const short* aG1 = aG0 + 16 * K_DIM;
    const short* bG0 = B + bRow0 * K_DIM + lq * 8;
    const short* bG1 = bG0 + 16 * K_DIM;
    short* aL0 = As + (2 * w) * 512;       // wave-uniform LDS bases
    short* aL1 = As + (2 * w + 1) * 512;
    short* bL0 = Bs + (2 * w) * 512;
    short* bL1 = Bs + (2 * w + 1) * 512;

    floatx4 acc[4][4];
    #pragma unroll
    for (int i = 0; i < 4; i++)
        #pragma unroll
        for (int j = 0; j < 4; j++)
            acc[i][j] = (floatx4){0.0f, 0.0f, 0.0f, 0.0f};

    for (int kb = 0; kb < K_DIM; kb += 32) {
        gload16(aG0 + kb, aL0);
        gload16(aG1 + kb, aL1);
        gload16(bG0 + kb, bL0);
        gload16(bG1 + kb, bL1);
        __syncthreads();  // drains vmcnt -> staging visible to all waves

        short8 af[4], bf[4];
        #pragma unroll
        for (int rt = 0; rt < 4; rt++) {
            af[rt] = *(const short8*)(As + (wm * 4 + rt) * 512 + l * 8);
            bf[rt] = *(const short8*)(Bs + (wn * 4 + rt) * 512 + l * 8);
        }
        #pragma unroll
        for (int rt = 0; rt < 4; rt++)
            #pragma unroll
            for (int ct = 0; ct < 4; ct++)
                acc[rt][ct] = __builtin_amdgcn_mfma_f32_16x16x32_bf16(
                    af[rt], bf[ct], acc[rt][ct], 0, 0, 0);
        __syncthreads();  // all reads done before next overwrite
    }

    // epilogue: C = acc * (weight_scale * scale) + bias
    float amax = __uint_as_float(*amax_u);
    float scale = amax * (1.0f / 127.0f);
    if (scale == 0.0f) scale = 1.0f;
    const float s = wscale[0] * scale;

    #pragma unroll
    for (int ct = 0; ct < 4; ct++) {
        const int col = nBase + wn * 64 + ct * 16 + lm;
        const float bb = bias[col];
        #pragma unroll
        for (int rt = 0; rt < 4; rt++) {
            const int row0 = mBase + wm * 64 + rt * 16 + lq * 4;
            #pragma unroll
            for (int r = 0; r < 4; r++) {
                C[(long)(row0 + r) * N_DIM + col] = acc[rt][ct][r] * s + bb;
            }
        }
    }
}

// ---------------------------------------------------------------------------
extern "C" void kernel_launch(void* const* d_in, const int* in_sizes, int n_in,
                              void* d_out, int out_size, void* d_ws, size_t ws_size,
                              hipStream_t stream) {
    const float* x      = (const float*)d_in[0];   // [8192,4096] fp32
    const int* weight   = (const int*)d_in[1];     // [4096,4096] int32 ternary
    const float* wscale = (const float*)d_in[2];   // scalar
    const float* bias   = (const float*)d_in[3];   // [4096]
    float* out          = (float*)d_out;           // [8192,4096] fp32

    unsigned char* ws = (unsigned char*)d_ws;
    unsigned* amax = (unsigned*)ws;                              // 4 B
    short* Aq = (short*)(ws + 256);                              // M*K bf16 = 64 MB
    short* Wb = (short*)(ws + 256 + (size_t)M_DIM * K_DIM * 2);  // N*K bf16 = 32 MB

    hipMemsetAsync(amax, 0, sizeof(unsigned), stream);

    absmax_kernel<<<2048, 256, 0, stream>>>((const float4*)x, amax,
                                            (M_DIM * K_DIM) / 4);
    quant_kernel<<<4096, 256, 0, stream>>>(x, Aq, amax, (size_t)M_DIM * K_DIM);
    wcvt_kernel<<<2048, 256, 0, stream>>>(weight, Wb, (size_t)N_DIM * K_DIM);

    dim3 grid(N_DIM / 128, M_DIM / 128);  // (32, 64)
    gemm_bt_bf16<<<grid, 256, 0, stream>>>(Aq, Wb, out, bias, wscale, amax);
}

// Round 2
// 557.768 us; speedup vs baseline: 1.5121x; 1.5121x over previous
//
#include <hip/hip_runtime.h>
#include <hip/hip_bf16.h>

#define M_DIM 8192
#define N_DIM 4096
#define K_DIM 4096

typedef __attribute__((ext_vector_type(4))) int int4v;

// ---------------------------------------------------------------------------
// Kernel 1: global absmax of x -> ws[0] (as uint bits; |x| bits compare ok)
// ---------------------------------------------------------------------------
__global__ void absmax_kernel(const float4* __restrict__ x, unsigned* __restrict__ amax,
                              int n4) {
    float m = 0.0f;
    for (int i = blockIdx.x * blockDim.x + threadIdx.x; i < n4;
         i += gridDim.x * blockDim.x) {
        float4 v = x[i];
        m = fmaxf(m, fmaxf(fmaxf(fabsf(v.x), fabsf(v.y)),
                           fmaxf(fabsf(v.z), fabsf(v.w))));
    }
    #pragma unroll
    for (int off = 32; off > 0; off >>= 1)
        m = fmaxf(m, __shfl_down(m, off, 64));
    __shared__ float sm[4];
    if ((threadIdx.x & 63) == 0) sm[threadIdx.x >> 6] = m;
    __syncthreads();
    if (threadIdx.x == 0) {
        float b = fmaxf(fmaxf(sm[0], sm[1]), fmaxf(sm[2], sm[3]));
        atomicMax(amax, __float_as_uint(b));
    }
}

// ---------------------------------------------------------------------------
// Kernel 2: quantize x -> int8 in [-128,127]. rintf = round-half-even = jnp.round
// ---------------------------------------------------------------------------
__global__ void quant_kernel(const float* __restrict__ x, char* __restrict__ q,
                             const unsigned* __restrict__ amax_u, size_t n) {
    float amax = __uint_as_float(*amax_u);
    float scale = amax * (1.0f / 127.0f);
    if (scale == 0.0f) scale = 1.0f;
    const float rs = 1.0f / scale;
    size_t stride = (size_t)gridDim.x * blockDim.x * 16;
    for (size_t i = ((size_t)blockIdx.x * blockDim.x + threadIdx.x) * 16; i < n;
         i += stride) {
        union { char c[16]; int4v v; } o;
        #pragma unroll
        for (int p = 0; p < 4; p++) {
            float4 v = *(const float4*)(x + i + p * 4);
            float f[4] = {v.x, v.y, v.z, v.w};
            #pragma unroll
            for (int j = 0; j < 4; j++) {
                float r = rintf(f[j] * rs);
                r = fminf(127.0f, fmaxf(-128.0f, r));
                o.c[p * 4 + j] = (char)(int)r;
            }
        }
        *(int4v*)(q + i) = o.v;
    }
}

// ---------------------------------------------------------------------------
// Kernel 3: ternary weight int32 -> int8
// ---------------------------------------------------------------------------
__global__ void wcvt_kernel(const int* __restrict__ w, char* __restrict__ q, size_t n) {
    size_t stride = (size_t)gridDim.x * blockDim.x * 16;
    for (size_t i = ((size_t)blockIdx.x * blockDim.x + threadIdx.x) * 16; i < n;
         i += stride) {
        union { char c[16]; int4v v; } o;
        #pragma unroll
        for (int p = 0; p < 4; p++) {
            int4 a = *(const int4*)(w + i + p * 4);
            o.c[p * 4 + 0] = (char)a.x;
            o.c[p * 4 + 1] = (char)a.y;
            o.c[p * 4 + 2] = (char)a.z;
            o.c[p * 4 + 3] = (char)a.w;
        }
        *(int4v*)(q + i) = o.v;
    }
}

// ---------------------------------------------------------------------------
// Kernel 4: i8 GEMM, B-transposed. A:[M,K] i8, B:[N,K] i8, C:[M,N] f32.
//   128x128 tile, BK=128, 32 K-iterations (4x fewer barriers than bf16 BK=32).
//   MFMA: i32_16x16x64_i8 (exact for int8 x ternary). LDS 32 KB/block.
//   LDS layout per matrix: 8 segs x [16 rows] x [2 k-chunks of 64] stored in
//   staging-lane order: seg*2048 + s*1024 + lane*16 (wave-uniform base + l*16
//   satisfies global_load_lds constraint AND the MFMA fragment read pattern:
//   lane l holds row (l&15), k = s*64 + (l>>4)*16 .. +16, contiguous bytes).
// ---------------------------------------------------------------------------
__device__ __forceinline__ void gload16(const char* g, char* l) {
    __builtin_amdgcn_global_load_lds(
        (const __attribute__((address_space(1))) unsigned int*)g,
        (__attribute__((address_space(3))) unsigned int*)l,
        16, 0, 0);
}

__global__ __launch_bounds__(256) void gemm_i8(
    const char* __restrict__ A,
    const char* __restrict__ B,
    float* __restrict__ C,
    const float* __restrict__ bias,
    const float* __restrict__ wscale,
    const unsigned* __restrict__ amax_u) {
    __shared__ __align__(16) char As[128 * 128];  // 16 KB
    __shared__ __align__(16) char Bs[128 * 128];  // 16 KB

    const int t = threadIdx.x;
    const int w = t >> 6;
    const int l = t & 63;
    const int lm = l & 15;
    const int lq = l >> 4;
    const int wm = w >> 1;
    const int wn = w & 1;

    const int mBase = blockIdx.y * 128;
    const int nBase = blockIdx.x * 128;

    // per-lane global base addresses for the two segments this wave stages
    const char* aG[2];
    const char* bG[2];
    char* aL[2];
    char* bL[2];
    #pragma unroll
    for (int i = 0; i < 2; i++) {
        const int seg = 2 * w + i;
        aG[i] = A + (size_t)(mBase + seg * 16 + lm) * K_DIM + lq * 16;
        bG[i] = B + (size_t)(nBase + seg * 16 + lm) * K_DIM + lq * 16;
        aL[i] = As + seg * 2048;
        bL[i] = Bs + seg * 2048;
    }

    int4v acc[4][4];
    #pragma unroll
    for (int i = 0; i < 4; i++)
        #pragma unroll
        for (int j = 0; j < 4; j++)
            acc[i][j] = (int4v){0, 0, 0, 0};

    for (int kb = 0; kb < K_DIM; kb += 128) {
        #pragma unroll
        for (int i = 0; i < 2; i++) {
            #pragma unroll
            for (int s = 0; s < 2; s++) {
                gload16(aG[i] + kb + s * 64, aL[i] + s * 1024);
                gload16(bG[i] + kb + s * 64, bL[i] + s * 1024);
            }
        }
        __syncthreads();

        #pragma unroll
        for (int s = 0; s < 2; s++) {
            int4v af[4], bf[4];
            #pragma unroll
            for (int rt = 0; rt < 4; rt++) {
                af[rt] = *(const int4v*)(As + (wm * 4 + rt) * 2048 + s * 1024 + l * 16);
                bf[rt] = *(const int4v*)(Bs + (wn * 4 + rt) * 2048 + s * 1024 + l * 16);
            }
            #pragma unroll
            for (int rt = 0; rt < 4; rt++)
                #pragma unroll
                for (int ct = 0; ct < 4; ct++)
                    acc[rt][ct] = __builtin_amdgcn_mfma_i32_16x16x64_i8(
                        af[rt], bf[ct], acc[rt][ct], 0, 0, 0);
        }
        __syncthreads();
    }

    // epilogue: C = acc_i32 * (weight_scale * scale) + bias
    float amax = __uint_as_float(*amax_u);
    float scale = amax * (1.0f / 127.0f);
    if (scale == 0.0f) scale = 1.0f;
    const float s = wscale[0] * scale;

    #pragma unroll
    for (int ct = 0; ct < 4; ct++) {
        const int col = nBase + wn * 64 + ct * 16 + lm;
        const float bb = bias[col];
        #pragma unroll
        for (int rt = 0; rt < 4; rt++) {
            const int row0 = mBase + wm * 64 + rt * 16 + lq * 4;
            #pragma unroll
            for (int r = 0; r < 4; r++) {
                C[(size_t)(row0 + r) * N_DIM + col] = (float)acc[rt][ct][r] * s + bb;
            }
        }
    }
}

// ---------------------------------------------------------------------------
extern "C" void kernel_launch(void* const* d_in, const int* in_sizes, int n_in,
                              void* d_out, int out_size, void* d_ws, size_t ws_size,
                              hipStream_t stream) {
    const float* x      = (const float*)d_in[0];   // [8192,4096] fp32
    const int* weight   = (const int*)d_in[1];     // [4096,4096] int32 ternary
    const float* wscale = (const float*)d_in[2];   // scalar
    const float* bias   = (const float*)d_in[3];   // [4096]
    float* out          = (float*)d_out;           // [8192,4096] fp32

    unsigned char* ws = (unsigned char*)d_ws;
    unsigned* amax = (unsigned*)ws;                             // 4 B
    char* Aq = (char*)(ws + 256);                               // M*K i8 = 32 MB
    char* Wb = (char*)(ws + 256 + (size_t)M_DIM * K_DIM);       // N*K i8 = 16 MB

    hipMemsetAsync(amax, 0, sizeof(unsigned), stream);

    absmax_kernel<<<2048, 256, 0, stream>>>((const float4*)x, amax,
                                            (M_DIM * K_DIM) / 4);
    quant_kernel<<<2048, 256, 0, stream>>>(x, Aq, amax, (size_t)M_DIM * K_DIM);
    wcvt_kernel<<<1024, 256, 0, stream>>>(weight, Wb, (size_t)N_DIM * K_DIM);

    dim3 grid(N_DIM / 128, M_DIM / 128);  // (32, 64)
    gemm_i8<<<grid, 256, 0, stream>>>(Aq, Wb, out, bias, wscale, amax);
}

// Round 3
// 542.110 us; speedup vs baseline: 1.5558x; 1.0289x over previous
//
#include <hip/hip_runtime.h>
#include <hip/hip_bf16.h>

#define M_DIM 8192
#define N_DIM 4096
#define K_DIM 4096

typedef __attribute__((ext_vector_type(4))) int int4v;

// ---------------------------------------------------------------------------
// pack 4 rounded/clamped floats (as ints) into one int32 (little-endian bytes)
// ---------------------------------------------------------------------------
__device__ __forceinline__ int quant4(float4 v, float rs) {
    float r0 = rintf(v.x * rs), r1 = rintf(v.y * rs);
    float r2 = rintf(v.z * rs), r3 = rintf(v.w * rs);
    int i0 = (int)fminf(127.0f, fmaxf(-128.0f, r0));
    int i1 = (int)fminf(127.0f, fmaxf(-128.0f, r1));
    int i2 = (int)fminf(127.0f, fmaxf(-128.0f, r2));
    int i3 = (int)fminf(127.0f, fmaxf(-128.0f, r3));
    return (i0 & 255) | ((i1 & 255) << 8) | ((i2 & 255) << 16) | (i3 << 24);
}

__device__ __forceinline__ int pack4i(int4 v) {
    return (v.x & 255) | ((v.y & 255) << 8) | ((v.z & 255) << 16) | (v.w << 24);
}

// ---------------------------------------------------------------------------
// P1: blocks [0,1024): ternary int32 weight -> int8 (independent of absmax)
//     blocks [1024,3072): absmax of x -> amax (uint bits, |x| >= 0)
// Exact partition, 4-way independent unrolled loads (MLP=4), no tails
// (sizes are compile-time multiples of the thread counts).
// ---------------------------------------------------------------------------
#define WCVT_BLOCKS 1024
#define ABS_BLOCKS 2048
__global__ void prep1_kernel(const float4* __restrict__ x,
                             const int4* __restrict__ w,
                             int* __restrict__ wq,
                             unsigned* __restrict__ amax) {
    if (blockIdx.x < WCVT_BLOCKS) {
        const int t = WCVT_BLOCKS * 256;
        const int n = (N_DIM * K_DIM) / 4;  // int4 count
        for (int i = blockIdx.x * 256 + threadIdx.x; i < n; i += 4 * t) {
            int4 a = w[i], b = w[i + t], c = w[i + 2 * t], d = w[i + 3 * t];
            wq[i] = pack4i(a);
            wq[i + t] = pack4i(b);
            wq[i + 2 * t] = pack4i(c);
            wq[i + 3 * t] = pack4i(d);
        }
    } else {
        const int t = ABS_BLOCKS * 256;
        const int n = (M_DIM * K_DIM) / 4;  // float4 count
        float m = 0.0f;
        for (int i = (blockIdx.x - WCVT_BLOCKS) * 256 + threadIdx.x; i < n;
             i += 4 * t) {
            float4 a = x[i], b = x[i + t], c = x[i + 2 * t], d = x[i + 3 * t];
            float ma = fmaxf(fmaxf(fabsf(a.x), fabsf(a.y)), fmaxf(fabsf(a.z), fabsf(a.w)));
            float mb = fmaxf(fmaxf(fabsf(b.x), fabsf(b.y)), fmaxf(fabsf(b.z), fabsf(b.w)));
            float mc = fmaxf(fmaxf(fabsf(c.x), fabsf(c.y)), fmaxf(fabsf(c.z), fabsf(c.w)));
            float md = fmaxf(fmaxf(fabsf(d.x), fabsf(d.y)), fmaxf(fabsf(d.z), fabsf(d.w)));
            m = fmaxf(m, fmaxf(fmaxf(ma, mb), fmaxf(mc, md)));
        }
        #pragma unroll
        for (int off = 32; off > 0; off >>= 1)
            m = fmaxf(m, __shfl_down(m, off, 64));
        __shared__ float sm[4];
        if ((threadIdx.x & 63) == 0) sm[threadIdx.x >> 6] = m;
        __syncthreads();
        if (threadIdx.x == 0) {
            float b = fmaxf(fmaxf(sm[0], sm[1]), fmaxf(sm[2], sm[3]));
            atomicMax(amax, __float_as_uint(b));
        }
    }
}

// ---------------------------------------------------------------------------
// P2: quantize x -> int8 (rintf = round-half-even = jnp.round, then clamp)
// ---------------------------------------------------------------------------
#define QUANT_BLOCKS 2048
__global__ void quant_kernel(const float4* __restrict__ x, int* __restrict__ q,
                             const unsigned* __restrict__ amax_u) {
    float amax = __uint_as_float(*amax_u);
    float scale = amax * (1.0f / 127.0f);
    if (scale == 0.0f) scale = 1.0f;
    const float rs = 1.0f / scale;
    const int t = QUANT_BLOCKS * 256;
    const int n = (M_DIM * K_DIM) / 4;  // float4 count (== int8x4 outputs)
    for (int i = blockIdx.x * 256 + threadIdx.x; i < n; i += 4 * t) {
        float4 a = x[i], b = x[i + t], c = x[i + 2 * t], d = x[i + 3 * t];
        q[i] = quant4(a, rs);
        q[i + t] = quant4(b, rs);
        q[i + 2 * t] = quant4(c, rs);
        q[i + 3 * t] = quant4(d, rs);
    }
}

// ---------------------------------------------------------------------------
// GEMM: i8, B-transposed. A:[M,K] i8, B:[N,K] i8, C:[M,N] f32.
//   128x128 tile, BK=128, 32 K-iters, mfma_i32_16x16x64_i8 (exact).
//   Grid launched 1D (2048); XCD-aware swizzle: f%8 = XCD (dispatch is
//   round-robin), each XCD gets a contiguous 16x16-tile patch (serpentine
//   within) so its 4MB L2 sees a compact A-band + B-band working set.
// ---------------------------------------------------------------------------
__device__ __forceinline__ void gload16(const char* g, char* l) {
    __builtin_amdgcn_global_load_lds(
        (const __attribute__((address_space(1))) unsigned int*)g,
        (__attribute__((address_space(3))) unsigned int*)l,
        16, 0, 0);
}

__global__ __launch_bounds__(256) void gemm_i8(
    const char* __restrict__ A,
    const char* __restrict__ B,
    float* __restrict__ C,
    const float* __restrict__ bias,
    const float* __restrict__ wscale,
    const unsigned* __restrict__ amax_u) {
    __shared__ __align__(16) char As[128 * 128];  // 16 KB
    __shared__ __align__(16) char Bs[128 * 128];  // 16 KB

    // ---- XCD-aware tile swizzle (perf-only heuristic) ----
    // 64 M-tiles x 32 N-tiles. 8 patches of 16x16 tiles: 4 along M, 2 along N.
    const int f = blockIdx.x;
    const int xcd = f & 7;
    const int slot = f >> 3;          // 0..255
    const int sm = slot >> 4;         // 0..15
    int sn = slot & 15;
    if (sm & 1) sn = 15 - sn;         // serpentine
    const int mBase = ((xcd >> 1) * 16 + sm) * 128;
    const int nBase = ((xcd & 1) * 16 + sn) * 128;

    const int t = threadIdx.x;
    const int w = t >> 6;
    const int l = t & 63;
    const int lm = l & 15;
    const int lq = l >> 4;
    const int wm = w >> 1;
    const int wn = w & 1;

    const char* aG[2];
    const char* bG[2];
    char* aL[2];
    char* bL[2];
    #pragma unroll
    for (int i = 0; i < 2; i++) {
        const int seg = 2 * w + i;
        aG[i] = A + (size_t)(mBase + seg * 16 + lm) * K_DIM + lq * 16;
        bG[i] = B + (size_t)(nBase + seg * 16 + lm) * K_DIM + lq * 16;
        aL[i] = As + seg * 2048;
        bL[i] = Bs + seg * 2048;
    }

    int4v acc[4][4];
    #pragma unroll
    for (int i = 0; i < 4; i++)
        #pragma unroll
        for (int j = 0; j < 4; j++)
            acc[i][j] = (int4v){0, 0, 0, 0};

    for (int kb = 0; kb < K_DIM; kb += 128) {
        #pragma unroll
        for (int i = 0; i < 2; i++) {
            #pragma unroll
            for (int s = 0; s < 2; s++) {
                gload16(aG[i] + kb + s * 64, aL[i] + s * 1024);
                gload16(bG[i] + kb + s * 64, bL[i] + s * 1024);
            }
        }
        __syncthreads();

        #pragma unroll
        for (int s = 0; s < 2; s++) {
            int4v af[4], bf[4];
            #pragma unroll
            for (int rt = 0; rt < 4; rt++) {
                af[rt] = *(const int4v*)(As + (wm * 4 + rt) * 2048 + s * 1024 + l * 16);
                bf[rt] = *(const int4v*)(Bs + (wn * 4 + rt) * 2048 + s * 1024 + l * 16);
            }
            #pragma unroll
            for (int rt = 0; rt < 4; rt++)
                #pragma unroll
                for (int ct = 0; ct < 4; ct++)
                    acc[rt][ct] = __builtin_amdgcn_mfma_i32_16x16x64_i8(
                        af[rt], bf[ct], acc[rt][ct], 0, 0, 0);
        }
        __syncthreads();
    }

    float amax = __uint_as_float(*amax_u);
    float scale = amax * (1.0f / 127.0f);
    if (scale == 0.0f) scale = 1.0f;
    const float s = wscale[0] * scale;

    #pragma unroll
    for (int ct = 0; ct < 4; ct++) {
        const int col = nBase + wn * 64 + ct * 16 + lm;
        const float bb = bias[col];
        #pragma unroll
        for (int rt = 0; rt < 4; rt++) {
            const int row0 = mBase + wm * 64 + rt * 16 + lq * 4;
            #pragma unroll
            for (int r = 0; r < 4; r++) {
                C[(size_t)(row0 + r) * N_DIM + col] = (float)acc[rt][ct][r] * s + bb;
            }
        }
    }
}

// ---------------------------------------------------------------------------
extern "C" void kernel_launch(void* const* d_in, const int* in_sizes, int n_in,
                              void* d_out, int out_size, void* d_ws, size_t ws_size,
                              hipStream_t stream) {
    const float* x      = (const float*)d_in[0];   // [8192,4096] fp32
    const int* weight   = (const int*)d_in[1];     // [4096,4096] int32 ternary
    const float* wscale = (const float*)d_in[2];   // scalar
    const float* bias   = (const float*)d_in[3];   // [4096]
    float* out          = (float*)d_out;           // [8192,4096] fp32

    unsigned char* ws = (unsigned char*)d_ws;
    unsigned* amax = (unsigned*)ws;                             // 4 B
    char* Aq = (char*)(ws + 256);                               // M*K i8 = 32 MB
    char* Wb = (char*)(ws + 256 + (size_t)M_DIM * K_DIM);       // N*K i8 = 16 MB

    hipMemsetAsync(amax, 0, sizeof(unsigned), stream);

    prep1_kernel<<<WCVT_BLOCKS + ABS_BLOCKS, 256, 0, stream>>>(
        (const float4*)x, (const int4*)weight, (int*)Wb, amax);
    quant_kernel<<<QUANT_BLOCKS, 256, 0, stream>>>((const float4*)x, (int*)Aq, amax);

    gemm_i8<<<2048, 256, 0, stream>>>(Aq, Wb, out, bias, wscale, amax);
}